// Round 1
// baseline (411.164 us; speedup 1.0000x reference)
//
#include <hip/hip_runtime.h>
#include <math.h>

#define N_NODES 50000
#define M_PAD   50048    // 391 * 128
#define E_EDGES 800000
#define IN_CH   128
#define C_CH    32
#define H_HEADS 8
#define HC      256      // H_HEADS * C_CH
#define BN_EPS  1e-5f
#define SLOPE   0.2f
#define LOG2E   1.44269504f

#define SCAN_CHUNK 512
#define SCAN_B     ((N_NODES + SCAN_CHUNK - 1) / SCAN_CHUNK)   // 98

typedef _Float16 f16x8 __attribute__((ext_vector_type(8)));
typedef _Float16 f16x4 __attribute__((ext_vector_type(4)));
typedef _Float16 f16x2 __attribute__((ext_vector_type(2)));
typedef float    f32x4 __attribute__((ext_vector_type(4)));

#if __has_builtin(__builtin_amdgcn_exp2f)
#define EXP2F(x) __builtin_amdgcn_exp2f(x)
#else
#define EXP2F(x) exp2f(x)
#endif

// ---------------- CSR build ----------------

__global__ void k_init_deg(int* deg, int n) {
    int i = blockIdx.x * blockDim.x + threadIdx.x;
    if (i < n) deg[i] = 1;              // self-loop contributes 1
}

__global__ void k_hist(const int* __restrict__ dst, int* deg, int e) {
    int i = blockIdx.x * blockDim.x + threadIdx.x;
    if (i < e) atomicAdd(&deg[dst[i]], 1);
}

// hierarchical scan, stage 1: per-chunk (512 elems) exclusive scan + chunk sum
__global__ __launch_bounds__(256) void k_scan_local(
        const int* __restrict__ deg, int* __restrict__ row_ptr,
        int* __restrict__ partials, int n) {
    __shared__ int sm[256];
    int t = threadIdx.x;
    int base = blockIdx.x * SCAN_CHUNK;
    int i0 = base + 2 * t, i1 = i0 + 1;
    int a = (i0 < n) ? deg[i0] : 0;
    int b = (i1 < n) ? deg[i1] : 0;
    int s = a + b;
    sm[t] = s;
    __syncthreads();
    #pragma unroll
    for (int off = 1; off < 256; off <<= 1) {
        int u = (t >= off) ? sm[t - off] : 0;
        __syncthreads();
        sm[t] += u;
        __syncthreads();
    }
    int excl = sm[t] - s;               // exclusive prefix of pair-sums
    if (i0 < n) row_ptr[i0] = excl;
    if (i1 < n) row_ptr[i1] = excl + a;
    if (t == 255) partials[blockIdx.x] = sm[255];
}

// stage 2: scan the chunk sums (SCAN_B <= 128), write total to row_ptr[n]
__global__ __launch_bounds__(128) void k_scan_part(
        int* __restrict__ partials, int* __restrict__ row_ptr_n) {
    __shared__ int sm[128];
    int t = threadIdx.x;
    int v = (t < SCAN_B) ? partials[t] : 0;
    sm[t] = v;
    __syncthreads();
    #pragma unroll
    for (int off = 1; off < 128; off <<= 1) {
        int u = (t >= off) ? sm[t - off] : 0;
        __syncthreads();
        sm[t] += u;
        __syncthreads();
    }
    if (t < SCAN_B) partials[t] = sm[t] - v;   // exclusive
    if (t == 127) *row_ptr_n = sm[127];        // total = E + N
}

// stage 3: add chunk offsets; produce row_ptr and cursor
__global__ void k_scan_add(int* __restrict__ row_ptr, int* __restrict__ cursor,
                           const int* __restrict__ partials, int n) {
    int i = blockIdx.x * blockDim.x + threadIdx.x;
    if (i < n) {
        int v = row_ptr[i] + partials[i / SCAN_CHUNK];
        row_ptr[i] = v;
        cursor[i] = v;
    }
}

__global__ void k_fill(const int* __restrict__ src, const int* __restrict__ dst,
                       int* cursor, int* csr_src, int e, int n) {
    int i = blockIdx.x * blockDim.x + threadIdx.x;
    if (i < e) {
        int d = dst[i];
        int p = atomicAdd(&cursor[d], 1);
        csr_src[p] = src[i];
    } else if (i < e + n) {
        int v = i - e;                  // self loop
        int p = atomicAdd(&cursor[v], 1);
        csr_src[p] = v;
    }
}

// ---------------- weight prep: all 4 W [K,256] -> Wt f16 [256][K] ----------------
// single-f16 weights: quant err ~3e-4 absolute on outputs (vs 7e-3 threshold).

__global__ void k_split_w4(const float* __restrict__ Wl0, const float* __restrict__ Wr0,
                           const float* __restrict__ Wl1, const float* __restrict__ Wr1,
                           _Float16* __restrict__ W0lt, _Float16* __restrict__ W0rt,
                           _Float16* __restrict__ W1lt, _Float16* __restrict__ W1rt) {
    int t = blockIdx.x * blockDim.x + threadIdx.x;
    const float* W; _Float16* O; int K, rel;
    if (t < 32768)       { W = Wl0; O = W0lt; K = 128; rel = t; }
    else if (t < 65536)  { W = Wr0; O = W0rt; K = 128; rel = t - 32768; }
    else if (t < 131072) { W = Wl1; O = W1lt; K = 256; rel = t - 65536; }
    else if (t < 196608) { W = Wr1; O = W1rt; K = 256; rel = t - 131072; }
    else return;
    int n = rel / K, k = rel - n * K;
    O[rel] = (_Float16)W[(size_t)k * 256 + n];
}

// ---------------- f16 MFMA GEMM, z-fused: C0 = A@W0, C1 = A@W1 ----------------
// A staged ONCE per block, both B tables consumed -> halves A HBM traffic and
// doubles MFMA per barrier vs the old blockIdx.z version.
// Tile: BM=128, BN=128, BK=32; 8 waves (512 thr); wave w owns rows [w*16,w*16+16).
// mfma_f32_16x16x32_f16 layouts (m89/m91-verified):
//   A: m=lane&15, k=(lane>>4)*8+j   B: n=lane&15, k=(lane>>4)*8+j
//   C/D: col=lane&15, row=(lane>>4)*4+reg

#define BK  32
#define LDA 40   // LDS row pitch in f16 (32 + 8 pad -> 80 B, 16B-aligned)

__device__ __forceinline__ f16x8 cvt_h8(float4 a, float4 b) {
    f16x8 v = { (_Float16)a.x, (_Float16)a.y, (_Float16)a.z, (_Float16)a.w,
                (_Float16)b.x, (_Float16)b.y, (_Float16)b.z, (_Float16)b.w };
    return v;
}

__global__ __launch_bounds__(512) void k_gemm_mfma(
        const _Float16* __restrict__ A16, const float* __restrict__ A32,
        const _Float16* __restrict__ W0t, const _Float16* __restrict__ W1t,
        _Float16* __restrict__ C0, _Float16* __restrict__ C1, int K) {
    __shared__ _Float16 As [128 * LDA];
    __shared__ _Float16 Bs0[128 * LDA];
    __shared__ _Float16 Bs1[128 * LDA];
    int t = threadIdx.x;
    int lane = t & 63, wv = t >> 6;           // 8 waves
    int quad = lane >> 4, r16 = lane & 15;
    size_t mBase = (size_t)blockIdx.x * 128;
    size_t nBase = (size_t)blockIdx.y * 128;
    int sr = t >> 2;              // staging row 0..127
    int sc = (t & 3) * 8;         // staging col (f16 units)
    f32x4 acc0[8] = {}, acc1[8] = {};
    for (int k0 = 0; k0 < K; k0 += BK) {
        if (A32) {
            size_t r0 = mBase + sr;
            float4 a0 = {0.f, 0.f, 0.f, 0.f}, a1 = a0;
            if (r0 < N_NODES) {
                const float* g = A32 + r0 * K + k0 + sc;
                a0 = ((const float4*)g)[0];
                a1 = ((const float4*)g)[1];
            }
            *(f16x8*)&As[sr * LDA + sc] = cvt_h8(a0, a1);
        } else {
            *(f16x8*)&As[sr * LDA + sc] =
                *(const f16x8*)(A16 + (size_t)(mBase + sr) * K + k0 + sc);
        }
        *(f16x8*)&Bs0[sr * LDA + sc] = *(const f16x8*)(W0t + (size_t)(nBase + sr) * K + k0 + sc);
        *(f16x8*)&Bs1[sr * LDA + sc] = *(const f16x8*)(W1t + (size_t)(nBase + sr) * K + k0 + sc);
        __syncthreads();
        f16x8 av = *(f16x8*)&As[(wv * 16 + r16) * LDA + quad * 8];
        #pragma unroll
        for (int ni = 0; ni < 8; ++ni) {
            f16x8 bv0 = *(f16x8*)&Bs0[(ni * 16 + r16) * LDA + quad * 8];
            f16x8 bv1 = *(f16x8*)&Bs1[(ni * 16 + r16) * LDA + quad * 8];
            acc0[ni] = __builtin_amdgcn_mfma_f32_16x16x32_f16(av, bv0, acc0[ni], 0, 0, 0);
            acc1[ni] = __builtin_amdgcn_mfma_f32_16x16x32_f16(av, bv1, acc1[ni], 0, 0, 0);
        }
        __syncthreads();
    }
    #pragma unroll
    for (int r = 0; r < 4; ++r) {
        size_t row = mBase + wv * 16 + quad * 4 + r;
        _Float16* cp0 = C0 + row * 256 + nBase + r16;
        _Float16* cp1 = C1 + row * 256 + nBase + r16;
        #pragma unroll
        for (int ni = 0; ni < 8; ++ni) {
            cp0[ni * 16] = (_Float16)acc0[ni][r];
            cp1[ni * 16] = (_Float16)acc1[ni][r];
        }
    }
}

// ---------------- edge pass: one wave per node, 2 edges/iter ----------------
// Each HALF-wave (32 lanes x f16x8 = 512 B, fully coalesced) owns one edge;
// lane q=lane&31 holds channels [q*8, q*8+8) -> head q>>2.
// Logit reduce is 2 shfl per 2 edges (vs 3 per edge before); exp count halved;
// att prescaled by log2(e) so exp -> raw v_exp_f32 (exp2).

__device__ __forceinline__ float edge_logit8(f16x8 h, f16x8 xr, f16x8 att) {
    f16x8 e = h + xr;                                    // 4x v_pk_add_f16
    f16x8 es = e * (_Float16)SLOPE;                      // 4x v_pk_mul_f16
    f16x8 l = __builtin_elementwise_max(e, es);          // 4x v_pk_max_f16 (slope<1)
#if __has_builtin(__builtin_amdgcn_fdot2)
    float p = __builtin_amdgcn_fdot2(__builtin_shufflevector(l, l, 0, 1),
                                     __builtin_shufflevector(att, att, 0, 1), 0.f, false);
    p = __builtin_amdgcn_fdot2(__builtin_shufflevector(l, l, 2, 3),
                               __builtin_shufflevector(att, att, 2, 3), p, false);
    p = __builtin_amdgcn_fdot2(__builtin_shufflevector(l, l, 4, 5),
                               __builtin_shufflevector(att, att, 4, 5), p, false);
    p = __builtin_amdgcn_fdot2(__builtin_shufflevector(l, l, 6, 7),
                               __builtin_shufflevector(att, att, 6, 7), p, false);
#else
    float p = 0.f;
    #pragma unroll
    for (int j = 0; j < 8; ++j) p = fmaf((float)l[j], (float)att[j], p);
#endif
    // head = q>>2: the head's 32 channels live in a 4-lane group (xor 1,2)
    p += __shfl_xor(p, 1);
    p += __shfl_xor(p, 2);
    return p;
}

__device__ __forceinline__ void edge_fma8(float* acc, f16x8 h, float w) {
    #pragma unroll
    for (int c = 0; c < 8; ++c) acc[c] = fmaf((float)h[c], w, acc[c]);  // v_fma_mix
}

// returns softmax denominator S (per head); acc[8] = sum_e w_e * xl[src_e][8ch]
__device__ __forceinline__ float edge_accum8(
        const f16x8* __restrict__ xl8q, f16x8 xr_h, f16x8 att_h,
        const int* __restrict__ csr_src, int beg, int end, int half,
        float* __restrict__ acc) {
    float S = 0.f;
    int j = beg;
    for (; j + 4 <= end; j += 4) {
        int sa = csr_src[j],     sb = csr_src[j + 1];     // uniform -> s_load
        int se = csr_src[j + 2], sd = csr_src[j + 3];
        int s0 = half ? sb : sa;
        int s1 = half ? sd : se;
        f16x8 h0 = xl8q[(size_t)s0 * 32];
        f16x8 h1 = xl8q[(size_t)s1 * 32];
        float p0 = edge_logit8(h0, xr_h, att_h);
        float p1 = edge_logit8(h1, xr_h, att_h);
        float w0 = EXP2F(p0), w1 = EXP2F(p1);
        S += w0 + w1;
        edge_fma8(acc, h0, w0);
        edge_fma8(acc, h1, w1);
    }
    int rem = end - j;
    if (rem > 0) {
        int sa = csr_src[j];
        int sb = (rem > 1) ? csr_src[j + 1] : sa;
        int s0 = half ? sb : sa;
        f16x8 h0 = xl8q[(size_t)s0 * 32];
        float p0 = edge_logit8(h0, xr_h, att_h);
        float w0 = (half && rem < 2) ? 0.f : EXP2F(p0);
        S += w0;
        edge_fma8(acc, h0, w0);
        if (rem == 3) {
            int s1 = csr_src[j + 2];
            f16x8 h1 = xl8q[(size_t)s1 * 32];
            float p1 = edge_logit8(h1, xr_h, att_h);
            float w1 = half ? 0.f : EXP2F(p1);
            S += w1;
            edge_fma8(acc, h1, w1);
        }
    }
    // merge the two half-wave partial sums (same channels in both halves)
    #pragma unroll
    for (int c = 0; c < 8; ++c) acc[c] += __shfl_xor(acc[c], 32);
    S += __shfl_xor(S, 32);
    return S;
}

__device__ __forceinline__ f16x8 att_load8(const float* __restrict__ att, int q) {
    f32x4 a0 = ((const f32x4*)att)[q * 2];
    f32x4 a1 = ((const f32x4*)att)[q * 2 + 1];
    f16x8 r = { (_Float16)(a0[0] * LOG2E), (_Float16)(a0[1] * LOG2E),
                (_Float16)(a0[2] * LOG2E), (_Float16)(a0[3] * LOG2E),
                (_Float16)(a1[0] * LOG2E), (_Float16)(a1[1] * LOG2E),
                (_Float16)(a1[2] * LOG2E), (_Float16)(a1[3] * LOG2E) };
    return r;
}

// layer 0: concat + bias + BN (folded to scale/shift) + ELU -> h0 (f16).
__global__ __launch_bounds__(256) void k_edge0(
        const _Float16* __restrict__ xl, const _Float16* __restrict__ xr,
        const float* __restrict__ att,
        const int* __restrict__ row_ptr, const int* __restrict__ csr_src,
        const float* __restrict__ b0, const float* __restrict__ g0,
        const float* __restrict__ be0, const float* __restrict__ m0,
        const float* __restrict__ v0,
        _Float16* __restrict__ h0) {
    int lane = threadIdx.x & 63;
    int q = lane & 31, half = lane >> 5;
    int i = __builtin_amdgcn_readfirstlane(blockIdx.x * 4 + (threadIdx.x >> 6));
    const f16x8* xl8q = (const f16x8*)xl + q;
    f16x8 xr_h = ((const f16x8*)xr)[(size_t)i * 32 + q];
    f16x8 att_h = att_load8(att, q);
    // BN fold: o = (msg + b - m)*rsqrt(v+eps)*g + be  =  msg*sc + sh
    float scv[8], shv[8];
    #pragma unroll
    for (int k = 0; k < 2; ++k) {
        f32x4 bb = ((const f32x4*)b0)[q * 2 + k];
        f32x4 gg = ((const f32x4*)g0)[q * 2 + k];
        f32x4 ee = ((const f32x4*)be0)[q * 2 + k];
        f32x4 mm = ((const f32x4*)m0)[q * 2 + k];
        f32x4 vv = ((const f32x4*)v0)[q * 2 + k];
        #pragma unroll
        for (int jj = 0; jj < 4; ++jj) {
            float s = rsqrtf(vv[jj] + BN_EPS) * gg[jj];
            scv[k * 4 + jj] = s;
            shv[k * 4 + jj] = (bb[jj] - mm[jj]) * s + ee[jj];
        }
    }
    int beg = row_ptr[i], end = row_ptr[i + 1];
    float acc[8] = {};
    float S = edge_accum8(xl8q, xr_h, att_h, csr_src, beg, end, half, acc);
    float inv = 1.f / S;
    f16x8 hh;
    #pragma unroll
    for (int c = 0; c < 8; ++c) {
        float o = acc[c] * inv * scv[c] + shv[c];
        o = o > 0.f ? o : expm1f(o);
        hh[c] = (_Float16)o;
    }
    if (half == 0)
        ((f16x8*)h0)[(size_t)i * 32 + q] = hh;
}

// layer 1: head-mean + bias + BN + classifier, fully in-register.
__global__ __launch_bounds__(256) void k_edge1(
        const _Float16* __restrict__ xl, const _Float16* __restrict__ xr,
        const float* __restrict__ att,
        const int* __restrict__ row_ptr, const int* __restrict__ csr_src,
        const float* __restrict__ b1, const float* __restrict__ g1,
        const float* __restrict__ be1, const float* __restrict__ m1,
        const float* __restrict__ v1,
        const float* __restrict__ Wc, const float* __restrict__ bc,
        float* __restrict__ out) {
    int lane = threadIdx.x & 63;
    int q = lane & 31, half = lane >> 5, cb = q & 3;
    int i = __builtin_amdgcn_readfirstlane(blockIdx.x * 4 + (threadIdx.x >> 6));
    const f16x8* xl8q = (const f16x8*)xl + q;
    f16x8 xr_h = ((const f16x8*)xr)[(size_t)i * 32 + q];
    f16x8 att_h = att_load8(att, q);
    int beg = row_ptr[i], end = row_ptr[i + 1];
    float acc[8] = {};
    float S = edge_accum8(xl8q, xr_h, att_h, csr_src, beg, end, half, acc);
    float inv = 1.f / S;
    float r[8];
    #pragma unroll
    for (int c = 0; c < 8; ++c) r[c] = acc[c] * inv;
    // head mean: lanes {cb, cb+4, ..., cb+28} hold the 8 heads of channel block cb
    #pragma unroll
    for (int mask = 4; mask <= 16; mask <<= 1)
        #pragma unroll
        for (int c = 0; c < 8; ++c) r[c] += __shfl_xor(r[c], mask);
    // r = sum over heads; 1/8 folded into BN scale. Then classifier partials.
    float o0 = 0.f, o1 = 0.f;
    #pragma unroll
    for (int k = 0; k < 2; ++k) {
        f32x4 bb = ((const f32x4*)b1)[cb * 2 + k];
        f32x4 gg = ((const f32x4*)g1)[cb * 2 + k];
        f32x4 ee = ((const f32x4*)be1)[cb * 2 + k];
        f32x4 mm = ((const f32x4*)m1)[cb * 2 + k];
        f32x4 vv = ((const f32x4*)v1)[cb * 2 + k];
        #pragma unroll
        for (int jj = 0; jj < 4; ++jj) {
            int c = k * 4 + jj;
            float s = rsqrtf(vv[jj] + BN_EPS) * gg[jj];
            float o = r[c] * (0.125f * s) + (bb[jj] - mm[jj]) * s + ee[jj];
            int ch = cb * 8 + c;
            float2 w = ((const float2*)Wc)[ch];
            o0 = fmaf(o, w.x, o0);
            o1 = fmaf(o, w.y, o1);
        }
    }
    // sum channel blocks across the 4-lane quad
    o0 += __shfl_xor(o0, 1); o0 += __shfl_xor(o0, 2);
    o1 += __shfl_xor(o1, 1); o1 += __shfl_xor(o1, 2);
    if (lane == 0) {
        float2 ov = {o0 + bc[0], o1 + bc[1]};
        *(float2*)(out + (size_t)i * 2) = ov;
    }
}

// ---------------- launcher ----------------

extern "C" void kernel_launch(void* const* d_in, const int* in_sizes, int n_in,
                              void* d_out, int out_size, void* d_ws, size_t ws_size,
                              hipStream_t stream) {
    const float* x    = (const float*)d_in[0];
    const int*   ei   = (const int*)d_in[1];
    const float* Wl0  = (const float*)d_in[2];
    const float* Wr0  = (const float*)d_in[3];
    const float* att0 = (const float*)d_in[4];
    const float* b0   = (const float*)d_in[5];
    const float* g0   = (const float*)d_in[6];
    const float* be0  = (const float*)d_in[7];
    const float* m0   = (const float*)d_in[8];
    const float* v0   = (const float*)d_in[9];
    const float* Wl1  = (const float*)d_in[10];
    const float* Wr1  = (const float*)d_in[11];
    const float* att1 = (const float*)d_in[12];
    const float* b1   = (const float*)d_in[13];
    const float* g1   = (const float*)d_in[14];
    const float* be1  = (const float*)d_in[15];
    const float* m1   = (const float*)d_in[16];
    const float* v1   = (const float*)d_in[17];
    const float* Wc   = (const float*)d_in[18];
    const float* bc   = (const float*)d_in[19];
    float* out = (float*)d_out;

    const int N = N_NODES, E = E_EDGES;
    const int* srcp = ei;        // edge_index[0]
    const int* dstp = ei + E;    // edge_index[1]

    // workspace carve-up (16B-aligned chunks)
    char* p = (char*)d_ws;
    _Float16* xlf = (_Float16*)p; p += (size_t)M_PAD * HC * 2;   // xl table [M_PAD,256] f16
    _Float16* xrf = (_Float16*)p; p += (size_t)M_PAD * HC * 2;   // xr table [M_PAD,256] f16
    _Float16* h0  = (_Float16*)p; p += (size_t)M_PAD * HC * 2;   // h0 [M_PAD,256] f16
    _Float16* W0lt = (_Float16*)p; p += (size_t)HC * IN_CH * 2;  // Wt of Wl0 [256][128]
    _Float16* W0rt = (_Float16*)p; p += (size_t)HC * IN_CH * 2;
    _Float16* W1lt = (_Float16*)p; p += (size_t)HC * HC * 2;     // Wt of Wl1 [256][256]
    _Float16* W1rt = (_Float16*)p; p += (size_t)HC * HC * 2;
    int* deg      = (int*)p;
    int* row_ptr  = deg + N;
    int* cursor   = row_ptr + (N + 1);
    int* partials = cursor + N;
    int* csr_src  = partials + ((SCAN_B + 3) & ~3);   // E+N entries

    // CSR build (by dst)
    k_init_deg<<<(N + 255) / 256, 256, 0, stream>>>(deg, N);
    k_hist<<<(E + 255) / 256, 256, 0, stream>>>(dstp, deg, E);
    k_scan_local<<<SCAN_B, 256, 0, stream>>>(deg, row_ptr, partials, N);
    k_scan_part<<<1, 128, 0, stream>>>(partials, row_ptr + N);
    k_scan_add<<<(N + 255) / 256, 256, 0, stream>>>(row_ptr, cursor, partials, N);
    k_fill<<<(E + N + 255) / 256, 256, 0, stream>>>(srcp, dstp, cursor, csr_src, E, N);

    // weight prep (single fused launch)
    k_split_w4<<<768, 256, 0, stream>>>(Wl0, Wr0, Wl1, Wr1, W0lt, W0rt, W1lt, W1rt);

    dim3 ggrid(M_PAD / 128, 2);
    // layer 0 projections: xl0 = x@Wl0, xr0 = x@Wr0 (fused, A staged once)
    k_gemm_mfma<<<ggrid, 512, 0, stream>>>(nullptr, x, W0lt, W0rt, xlf, xrf, IN_CH);
    // layer 0 edge pass + BN + ELU -> h0 (f16)
    k_edge0<<<N / 4, 256, 0, stream>>>(xlf, xrf, att0, row_ptr, csr_src,
                                       b0, g0, be0, m0, v0, h0);
    // layer 1 projections: xl1 = h0@Wl1, xr1 = h0@Wr1
    k_gemm_mfma<<<ggrid, 512, 0, stream>>>(h0, nullptr, W1lt, W1rt, xlf, xrf, HC);
    // layer 1 edge pass + head-mean + BN + classifier -> out
    k_edge1<<<N / 4, 256, 0, stream>>>(xlf, xrf, att1, row_ptr, csr_src,
                                       b1, g1, be1, m1, v1, Wc, bc, out);
}